// Round 1
// baseline (5354.300 us; speedup 1.0000x reference)
//
#include <hip/hip_runtime.h>
#include <hip/hip_fp16.h>

typedef _Float16 f16;
typedef __attribute__((ext_vector_type(8))) _Float16 f16x8;
typedef __attribute__((ext_vector_type(4))) float f32x4;

#define SWZ(r) ((((r)&3) ^ (((r)>>2)&3)))

// ---------------------------------------------------------------------------
// Core tile GEMM: C[128 x 64] = A[128 rows x K] * B(rows)[64 x K]^T
// A row-major (lda), B row-major (ldb); B tile row r -> global row
//   nbase + (r>>4)*nstride + (r&15)   (4 groups of 16 rows)
// Wave w (of 4) computes rows [w*32, w*32+32), all 64 cols as 2x4 16x16 tiles
// (nt indexes the 4 row-groups of B). acc[mt][nt][reg]:
//   row = w*32 + mt*16 + (lane>>4)*4 + reg, col-in-group = lane&15.
// Staging: global_load_lds 16B chunks, XOR-swizzled so ds_read_b128 is
// <=2-way bank aliased.
// ---------------------------------------------------------------------------
__device__ __forceinline__ void gemm_core(
    const f16* __restrict__ A, int lda,
    const f16* __restrict__ Bm, int ldb,
    int K, int bm0, int nbase, int nstride,
    f16* As, f16* Bs, f32x4 acc[2][4])
{
    const int tid  = threadIdx.x;
    const int wave = tid >> 6;
    const int lane = tid & 63;
    const int l15  = lane & 15;
    const int quad = lane >> 4;

    #pragma unroll
    for (int mt = 0; mt < 2; ++mt)
      #pragma unroll
      for (int nt = 0; nt < 4; ++nt)
        acc[mt][nt] = (f32x4){0.f, 0.f, 0.f, 0.f};

    // A: 128 rows x 32 cols f16 = 512 16B-chunks -> 2 passes of 256 threads
    const int cA0 = tid, cA1 = 256 + tid;
    const int rA0 = cA0 >> 2, rA1 = cA1 >> 2;
    const int kqA0 = (cA0 & 3) ^ SWZ(rA0);
    const int kqA1 = (cA1 & 3) ^ SWZ(rA1);
    const f16* gA0 = A + (size_t)(bm0 + rA0) * lda + kqA0 * 8;
    const f16* gA1 = A + (size_t)(bm0 + rA1) * lda + kqA1 * 8;
    // B: 64 rows x 32 cols = 256 chunks -> 1 pass
    const int rB  = tid >> 2;
    const int kqB = (tid & 3) ^ SWZ(rB);
    const int brow = nbase + (rB >> 4) * nstride + (rB & 15);
    const f16* gB = Bm + (size_t)brow * ldb + kqB * 8;

    // wave-uniform LDS destinations (HW: base + lane*16)
    f16* ldsA0 = As + wave * 512;
    f16* ldsA1 = As + 2048 + wave * 512;
    f16* ldsB  = Bs + wave * 512;

    // fragment LDS element offsets (chunk*8)
    int offA[2], offB[4];
    #pragma unroll
    for (int mt = 0; mt < 2; ++mt) {
        int r = wave * 32 + mt * 16 + l15;
        offA[mt] = (r * 4 + (quad ^ SWZ(r))) * 8;
    }
    #pragma unroll
    for (int nt = 0; nt < 4; ++nt) {
        int r = nt * 16 + l15;
        offB[nt] = (r * 4 + (quad ^ SWZ(r))) * 8;
    }

    for (int k0 = 0; k0 < K; k0 += 32) {
        __builtin_amdgcn_global_load_lds(
            (const __attribute__((address_space(1))) void*)(gA0 + k0),
            (__attribute__((address_space(3))) void*)ldsA0, 16, 0, 0);
        __builtin_amdgcn_global_load_lds(
            (const __attribute__((address_space(1))) void*)(gA1 + k0),
            (__attribute__((address_space(3))) void*)ldsA1, 16, 0, 0);
        __builtin_amdgcn_global_load_lds(
            (const __attribute__((address_space(1))) void*)(gB + k0),
            (__attribute__((address_space(3))) void*)ldsB, 16, 0, 0);
        __syncthreads();
        f16x8 af[2], bf[4];
        #pragma unroll
        for (int mt = 0; mt < 2; ++mt) af[mt] = *(const f16x8*)(As + offA[mt]);
        #pragma unroll
        for (int nt = 0; nt < 4; ++nt) bf[nt] = *(const f16x8*)(Bs + offB[nt]);
        #pragma unroll
        for (int mt = 0; mt < 2; ++mt)
          #pragma unroll
          for (int nt = 0; nt < 4; ++nt)
            acc[mt][nt] = __builtin_amdgcn_mfma_f32_16x16x32_f16(
                af[mt], bf[nt], acc[mt][nt], 0, 0, 0);
        __syncthreads();
    }
}

// ---------------------------------------------------------------------------
// One recurrent step (also step 0 with A=x0,K=128,W=W_ih):
//   gates = A @ W^T + bias ; cell ; write h (fp16) and c (fp32)
// Block computes [128 batch x 16 hidden] x 4 gates. nt == gate index, so the
// cell runs on registers (i,f,g,o share a lane).
// ---------------------------------------------------------------------------
__global__ __launch_bounds__(256, 2) void k_step(
    const f16* __restrict__ A, int lda, int K,
    const f16* __restrict__ W, int ldb,
    const float* __restrict__ bias,
    float* __restrict__ Cst,
    f16* __restrict__ Hout)
{
    __shared__ alignas(16) f16 As[4096];
    __shared__ alignas(16) f16 Bs[2048];
    const int hid0 = blockIdx.x * 16;
    const int bm0  = blockIdx.y * 128;
    f32x4 acc[2][4];
    gemm_core(A, lda, W, ldb, K, bm0, hid0, 2048, As, Bs, acc);

    const int lane = threadIdx.x & 63;
    const int wave = threadIdx.x >> 6;
    const int l15 = lane & 15, quad = lane >> 4;
    const int hid = hid0 + l15;
    const float bI = bias[hid];
    const float bF = bias[2048 + hid];
    const float bG = bias[4096 + hid];
    const float bO = bias[6144 + hid];
    #pragma unroll
    for (int mt = 0; mt < 2; ++mt) {
      #pragma unroll
      for (int reg = 0; reg < 4; ++reg) {
        const int row = bm0 + wave * 32 + mt * 16 + quad * 4 + reg;
        const size_t idx = (size_t)row * 2048 + hid;
        float iv = acc[mt][0][reg] + bI;
        float fv = acc[mt][1][reg] + bF;
        float gv = acc[mt][2][reg] + bG;
        float ov = acc[mt][3][reg] + bO;
        float si = 1.f / (1.f + __expf(-iv));
        float sf = 1.f / (1.f + __expf(-fv));
        float so = 1.f / (1.f + __expf(-ov));
        float tg = tanhf(gv);
        float c = sf * Cst[idx] + si * tg;
        Cst[idx] = c;
        Hout[idx] = (f16)(so * tanhf(c));
      }
    }
}

// out[b, t, d] = H[slot, b, :] @ W_out[d, :] + b_out[d];  t = t0 + slot
__global__ __launch_bounds__(256, 2) void k_out(
    const f16* __restrict__ Hbase,
    const f16* __restrict__ Wout,
    const float* __restrict__ bout,
    float* __restrict__ out, int t0)
{
    __shared__ alignas(16) f16 As[4096];
    __shared__ alignas(16) f16 Bs[2048];
    const int ng  = blockIdx.x;        // 0..1 : 64 output dims each
    const int bm0 = blockIdx.y * 128;  // over M = depth*512
    f32x4 acc[2][4];
    gemm_core(Hbase, 2048, Wout, 2048, 2048, bm0, ng * 64, 16, As, Bs, acc);
    const int lane = threadIdx.x & 63;
    const int wave = threadIdx.x >> 6;
    const int l15 = lane & 15, quad = lane >> 4;
    #pragma unroll
    for (int mt = 0; mt < 2; ++mt) {
      #pragma unroll
      for (int nt = 0; nt < 4; ++nt) {
        const int d = ng * 64 + nt * 16 + l15;
        const float bo = bout[d];
        #pragma unroll
        for (int reg = 0; reg < 4; ++reg) {
          const int m = bm0 + wave * 32 + mt * 16 + quad * 4 + reg;
          const int slot = m >> 9, b = m & 511;
          const int t = t0 + slot;
          out[(size_t)b * 16384 + t * 128 + d] = acc[mt][nt][reg] + bo;
        }
      }
    }
}

// ---------------- prep kernels (run once per launch) ------------------------

__global__ void k_cast(const float* __restrict__ s, f16* __restrict__ d, int n)
{
    int i = blockIdx.x * 256 + threadIdx.x;
    if (i < n) d[i] = (f16)s[i];
}

__global__ void k_x0(const float* __restrict__ tgt, f16* __restrict__ x0)
{
    int i = blockIdx.x * 256 + threadIdx.x;  // 65536 total
    int b = i >> 7, d = i & 127;
    x0[i] = (f16)tgt[(size_t)b * 16384 + d];  // tgt[b, 0, d]
}

__global__ void k_bias(const float* __restrict__ bih, const float* __restrict__ bhh,
                       const float* __restrict__ Wih, const float* __restrict__ bout,
                       float* __restrict__ b0, float* __restrict__ bp)
{
    int r = blockIdx.x * 256 + threadIdx.x;
    if (r >= 8192) return;
    float s = bih[r] + bhh[r];
    float a = 0.f;
    for (int d = 0; d < 128; ++d) a += Wih[(size_t)r * 128 + d] * bout[d];
    b0[r] = s;        // step-0 bias
    bp[r] = s + a;    // recurrent bias (absorbs W_ih @ b_out)
}

// W'[r,k] = W_hh[r,k] + sum_d W_ih[r,d] * W_out[d,k]  (fp32, cast to fp16)
__global__ __launch_bounds__(256) void k_wcomb(
    const float* __restrict__ Whh, const float* __restrict__ Wih,
    const float* __restrict__ Wout, f16* __restrict__ Wc)
{
    __shared__ float Ai[64 * 33];
    __shared__ float Bo[32 * 65];
    const int k0 = blockIdx.x * 64;
    const int r0 = blockIdx.y * 64;
    const int tid = threadIdx.x;
    const int tx = tid & 15, ty = tid >> 4;
    float acc[4][4] = {};
    for (int dc = 0; dc < 128; dc += 32) {
        for (int l = tid; l < 2048; l += 256) {
            int r = l >> 5, d = l & 31;
            Ai[r * 33 + d] = Wih[(size_t)(r0 + r) * 128 + dc + d];
        }
        for (int l = tid; l < 2048; l += 256) {
            int d = l >> 6, k = l & 63;
            Bo[d * 65 + k] = Wout[(size_t)(dc + d) * 2048 + k0 + k];
        }
        __syncthreads();
        #pragma unroll 8
        for (int d = 0; d < 32; ++d) {
            float a[4], b[4];
            #pragma unroll
            for (int i = 0; i < 4; ++i) a[i] = Ai[(ty * 4 + i) * 33 + d];
            #pragma unroll
            for (int j = 0; j < 4; ++j) b[j] = Bo[d * 65 + tx * 4 + j];
            #pragma unroll
            for (int i = 0; i < 4; ++i)
              #pragma unroll
              for (int j = 0; j < 4; ++j)
                acc[i][j] += a[i] * b[j];
        }
        __syncthreads();
    }
    #pragma unroll
    for (int i = 0; i < 4; ++i)
      #pragma unroll
      for (int j = 0; j < 4; ++j) {
        int r = r0 + ty * 4 + i, k = k0 + tx * 4 + j;
        Wc[(size_t)r * 2048 + k] = (f16)(acc[i][j] + Whh[(size_t)r * 2048 + k]);
      }
}

// ---------------------------------------------------------------------------

extern "C" void kernel_launch(void* const* d_in, const int* in_sizes, int n_in,
                              void* d_out, int out_size, void* d_ws, size_t ws_size,
                              hipStream_t stream)
{
    const float* tgt  = (const float*)d_in[0];
    const float* Wih  = (const float*)d_in[1];
    const float* Whh  = (const float*)d_in[2];
    const float* bih  = (const float*)d_in[3];
    const float* bhh  = (const float*)d_in[4];
    const float* Wout = (const float*)d_in[5];
    const float* bout = (const float*)d_in[6];
    float* out = (float*)d_out;

    char* ws = (char*)d_ws;
    size_t off = 0;
    auto alloc = [&](size_t bytes) -> void* {
        void* p = ws + off;
        off += (bytes + 255) & ~(size_t)255;
        return p;
    };
    f16*   Wc     = (f16*)alloc((size_t)8192 * 2048 * 2);  // combined W_hh + W_ih*W_out
    f16*   Wih16  = (f16*)alloc((size_t)8192 * 128 * 2);
    f16*   Wout16 = (f16*)alloc((size_t)128 * 2048 * 2);
    f16*   x0     = (f16*)alloc((size_t)512 * 128 * 2);
    float* b0     = (float*)alloc(8192 * 4);
    float* bp     = (float*)alloc(8192 * 4);
    float* Cst    = (float*)alloc((size_t)512 * 2048 * 4);

    const size_t slotsz = (size_t)512 * 2048;  // elements per h snapshot
    int depth = 0;
    const int cands[7] = {128, 64, 32, 16, 8, 4, 2};
    for (int i = 0; i < 7; ++i)
        if (off + (size_t)cands[i] * slotsz * 2 <= ws_size) { depth = cands[i]; break; }
    if (depth == 0) return;  // workspace too small for any configuration
    f16* Hbuf = (f16*)alloc((size_t)depth * slotsz * 2);

    hipMemsetAsync(Cst, 0, (size_t)512 * 2048 * 4, stream);
    k_cast<<<dim3(4096), dim3(256), 0, stream>>>(Wih, Wih16, 1048576);
    k_cast<<<dim3(1024), dim3(256), 0, stream>>>(Wout, Wout16, 262144);
    k_x0<<<dim3(256), dim3(256), 0, stream>>>(tgt, x0);
    k_bias<<<dim3(32), dim3(256), 0, stream>>>(bih, bhh, Wih, bout, b0, bp);
    k_wcomb<<<dim3(32, 128), dim3(256), 0, stream>>>(Whh, Wih, Wout, Wc);

    // step 0: gates = x0 @ W_ih^T + (b_ih+b_hh)  -> h^1 in slot 0
    k_step<<<dim3(128, 4), dim3(256), 0, stream>>>(x0, 128, 128, Wih16, 128, b0, Cst, Hbuf);
    // steps 1..127: gates = h @ W'^T + b'
    for (int s = 1; s < 128; ++s) {
        if ((s % depth) == 0)  // slots 0..depth-1 hold h^(s-depth+1..s) -> out t in [s-depth, s)
            k_out<<<dim3(2, depth * 4), dim3(256), 0, stream>>>(Hbuf, Wout16, bout, out, s - depth);
        k_step<<<dim3(128, 4), dim3(256), 0, stream>>>(
            Hbuf + (size_t)((s - 1) % depth) * slotsz, 2048, 2048, Wc, 2048, bp,
            Cst, Hbuf + (size_t)(s % depth) * slotsz);
    }
    k_out<<<dim3(2, depth * 4), dim3(256), 0, stream>>>(Hbuf, Wout16, bout, out, 128 - depth);
}